// Round 1
// 1815.456 us; speedup vs baseline: 1.1806x; 1.1806x over previous
//
#include <hip/hip_runtime.h>

typedef __attribute__((ext_vector_type(8))) short bf16x8;
typedef __attribute__((ext_vector_type(4))) float f32x4;

#define P_DIM 65536
#define N_DIM 4096
#define C_DIM 200
#define C_PAD 256
#define HID   128
#define H2    64
#define NCLS  16

// RNE float -> bf16 (inputs finite)
__device__ __forceinline__ unsigned short f2bu(float f) {
  unsigned int u = __float_as_uint(f);
  u += 0x7fffu + ((u >> 16) & 1u);
  return (unsigned short)(u >> 16);
}

// async global->LDS, 16B per lane. LDS dest must be wave-uniform base + lane*16.
__device__ __forceinline__ void gl_lds16(const void* g, void* l) {
  __builtin_amdgcn_global_load_lds(
      (const __attribute__((address_space(1))) unsigned int*)g,
      (__attribute__((address_space(3))) unsigned int*)l, 16, 0, 0);
}

// ---------------------------------------------------------------------------
// prep_x: x [P][200] fp32 -> xfTb [256][P] bf16 transposed, rows >=200 zero.
__global__ __launch_bounds__(256) void k_prep_x(const float* __restrict__ X,
    unsigned short* __restrict__ xfTb) {
  __shared__ unsigned short ldsT[64][68];
  const int t = threadIdx.x;
  const int pb = blockIdx.x * 64;
  const int cb = blockIdx.y * 64;
  const int R  = t >> 4;
  const int c4 = (t & 15) << 2;
  const int cg = cb + c4;
  float vals[4][4];
#pragma unroll
  for (int j = 0; j < 4; ++j) {
    float4 v = make_float4(0.f, 0.f, 0.f, 0.f);
    if (cg < C_DIM)
      v = *reinterpret_cast<const float4*>(X + (size_t)(pb + 4 * R + j) * C_DIM + cg);
    vals[j][0] = v.x; vals[j][1] = v.y; vals[j][2] = v.z; vals[j][3] = v.w;
  }
#pragma unroll
  for (int i = 0; i < 4; ++i) {
    ushort4 u;
    u.x = f2bu(vals[0][i]); u.y = f2bu(vals[1][i]);
    u.z = f2bu(vals[2][i]); u.w = f2bu(vals[3][i]);
    *reinterpret_cast<ushort4*>(&ldsT[c4 + i][4 * R]) = u;
  }
  __syncthreads();
  const int n  = t >> 2;
  const int po = (t & 3) << 4;
  ushort4 a0 = *reinterpret_cast<ushort4*>(&ldsT[n][po + 0]);
  ushort4 a1 = *reinterpret_cast<ushort4*>(&ldsT[n][po + 4]);
  ushort4 a2 = *reinterpret_cast<ushort4*>(&ldsT[n][po + 8]);
  ushort4 a3 = *reinterpret_cast<ushort4*>(&ldsT[n][po + 12]);
  unsigned short* dst = xfTb + (size_t)(cb + n) * P_DIM + pb + po;
  *reinterpret_cast<ushort4*>(dst + 0)  = a0;
  *reinterpret_cast<ushort4*>(dst + 4)  = a1;
  *reinterpret_cast<ushort4*>(dst + 8)  = a2;
  *reinterpret_cast<ushort4*>(dst + 12) = a3;
}

// prep_A: straight fp32 -> bf16 convert, 16.7M elems, grid 16384 x 256.
__global__ __launch_bounds__(256) void k_prep_A(const float* __restrict__ A,
    unsigned short* __restrict__ Ab) {
  const size_t i = ((size_t)blockIdx.x * 256 + threadIdx.x) * 4;
  const float4 v = *reinterpret_cast<const float4*>(A + i);
  ushort4 u;
  u.x = f2bu(v.x); u.y = f2bu(v.y); u.z = f2bu(v.z); u.w = f2bu(v.w);
  *reinterpret_cast<ushort4*>(Ab + i) = u;
}

// ---------------------------------------------------------------------------
// gemm1 (FUSED): Sun[4096][256] += Q^T @ xf, reading Q fp32 directly.
//   A-op staged via in-kernel register-transpose + bf16 convert into
//   XOR-swizzled LDS ([m][k], k ^= ((m>>2)&7)*8 -> ~4-way conflicts both sides).
//   colsum[n] (fp32, pre-convert values) accumulated on the way through.
// Tile 128m x 256n, BK=64, 512 thr (8 waves, 2m x 4n of 64x64), splitK=16.
__global__ __launch_bounds__(512) void k_gemm1(const float* __restrict__ Q,
    const unsigned short* __restrict__ xfTb, float* __restrict__ Sun,
    float* __restrict__ colsum) {
  __shared__ unsigned short lA[128 * 64];   // [m][k] bf16, k swizzled
  __shared__ unsigned short lB[256 * 64];   // [c][k] bf16, linear (gl_lds16)
  const int t = threadIdx.x;
  const int l = t & 63;
  const int w = t >> 6;
  const int wm = w >> 2, wn = w & 3;
  const int m0 = blockIdx.x * 128;
  const int kbase = blockIdx.y * (P_DIM / 16);

  // A-load mapping: 4x4 fp32 subtile per thread.
  // lanes 0..31 of a wave cover 128 n (512B contiguous) of one p-row.
  const int mq = t & 31;        // n-group: cols m0 + mq*4 .. +3
  const int kq = t >> 5;        // p-group: rows kq*4 .. +3 within BK=64
  const int kphys = (kq * 4) ^ ((mq & 7) * 8);   // swizzled k slot for writes

  f32x4 acc[4][4];
#pragma unroll
  for (int i = 0; i < 4; ++i)
#pragma unroll
    for (int j = 0; j < 4; ++j) acc[i][j] = (f32x4){0.f, 0.f, 0.f, 0.f};
  float csum[4] = {0.f, 0.f, 0.f, 0.f};

  const float* gQ = Q + (size_t)(kbase + kq * 4) * N_DIM + m0 + mq * 4;
  const unsigned short* gB = xfTb + (size_t)(t >> 3) * P_DIM + kbase + (t & 7) * 8;
  char* lBp = reinterpret_cast<char*>(lB) + t * 16;
  const int am = wm * 64 + (l & 15);
  const int bc = wn * 64 + (l & 15);

  for (int kk = 0; kk < P_DIM / 16; kk += 64) {
    // B: 4 async 16B/lane loads fill lB [256][64] linearly.
#pragma unroll
    for (int r = 0; r < 4; ++r)
      gl_lds16(gB + kk + (size_t)(r * 64) * P_DIM, lBp + r * 8192);
    // A: 4 coalesced float4 rows, register transpose + cvt + swizzled ds_write.
    float4 v[4];
#pragma unroll
    for (int j = 0; j < 4; ++j)
      v[j] = *reinterpret_cast<const float4*>(gQ + (size_t)(kk + j) * N_DIM);
    const float* fv = reinterpret_cast<const float*>(v);
#pragma unroll
    for (int i = 0; i < 4; ++i) {
      const float a0 = fv[0 + i], a1 = fv[4 + i], a2 = fv[8 + i], a3 = fv[12 + i];
      csum[i] += (a0 + a1) + (a2 + a3);
      ushort4 u;
      u.x = f2bu(a0); u.y = f2bu(a1); u.z = f2bu(a2); u.w = f2bu(a3);
      *reinterpret_cast<ushort4*>(&lA[(mq * 4 + i) * 64 + kphys]) = u;
    }
    __syncthreads();
#pragma unroll
    for (int ks = 0; ks < 2; ++ks) {
      const int kf = ks * 32 + (l >> 4) * 8;
      bf16x8 af[4], bfr[4];
#pragma unroll
      for (int i = 0; i < 4; ++i) {
        const int m = am + i * 16;
        af[i] = *reinterpret_cast<const bf16x8*>(
            &lA[m * 64 + (kf ^ (((m >> 2) & 7) * 8))]);
      }
#pragma unroll
      for (int j = 0; j < 4; ++j)
        bfr[j] = *reinterpret_cast<const bf16x8*>(&lB[(bc + j * 16) * 64 + kf]);
#pragma unroll
      for (int i = 0; i < 4; ++i)
#pragma unroll
        for (int j = 0; j < 4; ++j)
          acc[i][j] = __builtin_amdgcn_mfma_f32_16x16x32_bf16(af[i], bfr[j], acc[i][j], 0, 0, 0);
    }
    __syncthreads();
  }

  // colsum reduction: reuse lA as fp32 scratch [16 kq][128 n].
  float* cs = reinterpret_cast<float*>(lA);
#pragma unroll
  for (int i = 0; i < 4; ++i) cs[kq * 128 + mq * 4 + i] = csum[i];
  __syncthreads();
  if (t < 128) {
    float s = 0.f;
#pragma unroll
    for (int r = 0; r < 16; ++r) s += cs[r * 128 + t];
    atomicAdd(colsum + m0 + t, s);
  }

#pragma unroll
  for (int i = 0; i < 4; ++i) {
    const int row = m0 + wm * 64 + i * 16 + (l >> 4) * 4;
#pragma unroll
    for (int j = 0; j < 4; ++j) {
      const int col = wn * 64 + j * 16 + (l & 15);
#pragma unroll
      for (int r = 0; r < 4; ++r)
        atomicAdd(Sun + (size_t)(row + r) * C_PAD + col, acc[i][j][r]);
    }
  }
}

// generic A@B (both K=4096, K-contig bf16), 128xBN tile, 256 thr, splitK=8.
template <int BN>
__global__ __launch_bounds__(256) void k_gemm_at(const unsigned short* __restrict__ Am,
    const unsigned short* __restrict__ Bm, float* __restrict__ Cm) {
  __shared__ unsigned short lA[128 * 32];
  __shared__ unsigned short lB[BN * 32];
  const int t = threadIdx.x;
  const int l = t & 63;
  const int w = t >> 6;
  const int wm = w >> 1, wn = w & 1;
  const int m0 = blockIdx.x * 128;
  const int kbase = blockIdx.y * 512;
  constexpr int FN = BN / 32;
  f32x4 acc[4][FN];
#pragma unroll
  for (int i = 0; i < 4; ++i)
#pragma unroll
    for (int j = 0; j < FN; ++j) acc[i][j] = (f32x4){0.f, 0.f, 0.f, 0.f};
  const int sk = (t & 3) * 8;
  const unsigned short* gA = Am + (size_t)(m0 + (t >> 2)) * 4096 + kbase + sk;
  const unsigned short* gB = Bm + (size_t)(t >> 2) * 4096 + kbase + sk;
  char* lAp = reinterpret_cast<char*>(lA) + t * 16;
  char* lBp = reinterpret_cast<char*>(lB) + t * 16;
  const int la_off = (wm * 64 + (l & 15)) * 32 + (l >> 4) * 8;
  const int lb_off = (wn * (BN / 2) + (l & 15)) * 32 + (l >> 4) * 8;
  for (int kk = 0; kk < 512; kk += 32) {
    gl_lds16(gA + kk, lAp);
    gl_lds16(gA + (size_t)64 * 4096 + kk, lAp + 4096);
    gl_lds16(gB + kk, lBp);
    if constexpr (BN == 128) gl_lds16(gB + (size_t)64 * 4096 + kk, lBp + 4096);
    __syncthreads();
    bf16x8 af[4], bfr[FN];
#pragma unroll
    for (int i = 0; i < 4; ++i)
      af[i] = *reinterpret_cast<const bf16x8*>(lA + la_off + i * 512);
#pragma unroll
    for (int j = 0; j < FN; ++j)
      bfr[j] = *reinterpret_cast<const bf16x8*>(lB + lb_off + j * 512);
#pragma unroll
    for (int i = 0; i < 4; ++i)
#pragma unroll
      for (int j = 0; j < FN; ++j)
        acc[i][j] = __builtin_amdgcn_mfma_f32_16x16x32_bf16(af[i], bfr[j], acc[i][j], 0, 0, 0);
    __syncthreads();
  }
#pragma unroll
  for (int i = 0; i < 4; ++i) {
    const int row = m0 + wm * 64 + i * 16 + (l >> 4) * 4;
#pragma unroll
    for (int j = 0; j < FN; ++j) {
      const int col = wn * (BN / 2) + j * 16 + (l & 15);
#pragma unroll
      for (int r = 0; r < 4; ++r)
        atomicAdd(Cm + (size_t)(row + r) * BN + col, acc[i][j][r]);
    }
  }
}

// ---------------------------------------------------------------------------
// fc1: t1T[h][n] = sum_c (Sun[n][c]/colsum[n]) * W1[c][h] + b1[h], bf16 out.
__global__ __launch_bounds__(128) void k_fc1(const float* __restrict__ Sun,
    const float* __restrict__ colsum, const float* __restrict__ W1,
    const float* __restrict__ b1, unsigned short* __restrict__ t1T) {
  __shared__ float sv[C_DIM];
  const int n = blockIdx.x, t = threadIdx.x;
  const float inv = 1.0f / colsum[n];
  for (int c = t; c < C_DIM; c += 128) sv[c] = Sun[(size_t)n * C_PAD + c] * inv;
  __syncthreads();
  float acc = b1[t];
#pragma unroll 8
  for (int c = 0; c < C_DIM; ++c) acc = fmaf(sv[c], W1[c * HID + t], acc);
  t1T[(size_t)t * N_DIM + n] = f2bu(acc);
}

// BN stats per column: bnp[h] = (scale, shift) folding gamma/beta/mean/rstd.
template <int NC>
__global__ __launch_bounds__(256) void k_bnstats(const float* __restrict__ X,
    const float* __restrict__ g, const float* __restrict__ b,
    float2* __restrict__ bnp) {
  const int h = blockIdx.x, t = threadIdx.x;
  float s = 0.f, q = 0.f;
  for (int n = t; n < N_DIM; n += 256) {
    const float v = X[(size_t)n * NC + h];
    s += v; q += v * v;
  }
#pragma unroll
  for (int d = 32; d; d >>= 1) { s += __shfl_down(s, d); q += __shfl_down(q, d); }
  __shared__ float rs[4], rq[4];
  if ((t & 63) == 0) { rs[t >> 6] = s; rq[t >> 6] = q; }
  __syncthreads();
  if (t == 0) {
    s = rs[0] + rs[1] + rs[2] + rs[3];
    q = rq[0] + rq[1] + rq[2] + rq[3];
    const float mean = s * (1.f / N_DIM);
    const float var  = q * (1.f / N_DIM) - mean * mean;
    const float rstd = rsqrtf(var + 1e-5f);
    const float sc = g[h] * rstd;
    bnp[h] = make_float2(sc, b[h] - mean * sc);
  }
}

// fc2: t2T[j][n] = sum_c relu(bn(s1[n][c])) * W2[c][j] + b2[j]
__global__ __launch_bounds__(64) void k_fc2(const float* __restrict__ s1,
    const float2* __restrict__ bnp, const float* __restrict__ W2,
    const float* __restrict__ b2, unsigned short* __restrict__ t2T) {
  __shared__ float sv[HID];
  const int n = blockIdx.x, t = threadIdx.x;
#pragma unroll
  for (int c = t; c < HID; c += 64) {
    const float2 p = bnp[c];
    sv[c] = fmaxf(fmaf(s1[(size_t)n * HID + c], p.x, p.y), 0.f);
  }
  __syncthreads();
  float acc = b2[t];
#pragma unroll 8
  for (int c = 0; c < HID; ++c) acc = fmaf(sv[c], W2[c * H2 + t], acc);
  t2T[(size_t)t * N_DIM + n] = f2bu(acc);
}

// fc3: s3T[j][n] = sum_c relu(bn(s2[n][c])) * lin_w[j][c] + lin_b[j]
__global__ __launch_bounds__(64) void k_fc3(const float* __restrict__ s2,
    const float2* __restrict__ bnp, const float* __restrict__ lw,
    const float* __restrict__ lb, unsigned short* __restrict__ s3T) {
  __shared__ float sv[H2];
  const int n = blockIdx.x, t = threadIdx.x;
  {
    const float2 p = bnp[t];
    sv[t] = fmaxf(fmaf(s2[(size_t)n * H2 + t], p.x, p.y), 0.f);
  }
  __syncthreads();
  if (t < NCLS) {
    float acc = lb[t];
#pragma unroll 8
    for (int c = 0; c < H2; ++c) acc = fmaf(sv[c], lw[t * H2 + c], acc);
    s3T[(size_t)t * N_DIM + n] = f2bu(acc);
  }
}

// gemm4 + softmax: out[p][j] = softmax_j( sum_n Q[p][n]*s3[n][j] ).
// wave = 16 p-rows, A from fp32 Q (in-register bf16 cvt), B = s3T L2-hot.
__global__ __launch_bounds__(256) void k_gemm4(const float* __restrict__ Q,
    const unsigned short* __restrict__ s3T, float* __restrict__ out) {
  const int t = threadIdx.x;
  const int l = t & 63;
  const int w = t >> 6;
  const int pbase = blockIdx.x * 64 + w * 16;
  const float* qrow = Q + (size_t)(pbase + (l & 15)) * N_DIM;
  const unsigned short* brow = s3T + (size_t)(l & 15) * N_DIM;
  const int ko0 = (l >> 4) * 8;
  f32x4 acc = (f32x4){0.f, 0.f, 0.f, 0.f};
#pragma unroll 2
  for (int k = 0; k < N_DIM; k += 32) {
    const int ko = k + ko0;
    const float4 a0 = *reinterpret_cast<const float4*>(qrow + ko);
    const float4 a1 = *reinterpret_cast<const float4*>(qrow + ko + 4);
    bf16x8 af;
    af[0] = (short)f2bu(a0.x); af[1] = (short)f2bu(a0.y);
    af[2] = (short)f2bu(a0.z); af[3] = (short)f2bu(a0.w);
    af[4] = (short)f2bu(a1.x); af[5] = (short)f2bu(a1.y);
    af[6] = (short)f2bu(a1.z); af[7] = (short)f2bu(a1.w);
    const bf16x8 bfr = *reinterpret_cast<const bf16x8*>(brow + ko);
    acc = __builtin_amdgcn_mfma_f32_16x16x32_bf16(af, bfr, acc, 0, 0, 0);
  }
  const int col = l & 15;
#pragma unroll
  for (int r = 0; r < 4; ++r) {
    const float xv = acc[r];
    float mx = xv;
    mx = fmaxf(mx, __shfl_xor(mx, 1));
    mx = fmaxf(mx, __shfl_xor(mx, 2));
    mx = fmaxf(mx, __shfl_xor(mx, 4));
    mx = fmaxf(mx, __shfl_xor(mx, 8));
    const float e = __expf(xv - mx);
    float s = e;
    s += __shfl_xor(s, 1);
    s += __shfl_xor(s, 2);
    s += __shfl_xor(s, 4);
    s += __shfl_xor(s, 8);
    const int prow = pbase + (l >> 4) * 4 + r;
    out[(size_t)prow * NCLS + col] = e / s;
  }
}

// ---------------------------------------------------------------------------
extern "C" void kernel_launch(void* const* d_in, const int* in_sizes, int n_in,
                              void* d_out, int out_size, void* d_ws, size_t ws_size,
                              hipStream_t stream) {
  const float* x     = (const float*)d_in[0];
  const float* Q     = (const float*)d_in[1];
  const float* A     = (const float*)d_in[2];
  const float* W1    = (const float*)d_in[3];
  const float* b1    = (const float*)d_in[4];
  const float* W2    = (const float*)d_in[5];
  const float* b2    = (const float*)d_in[6];
  const float* g2    = (const float*)d_in[7];
  const float* beta2 = (const float*)d_in[8];
  const float* g3    = (const float*)d_in[9];
  const float* beta3 = (const float*)d_in[10];
  const float* lin_w = (const float*)d_in[11];
  const float* lin_b = (const float*)d_in[12];
  float* out = (float*)d_out;

  char* w = (char*)d_ws;
  auto alloc = [&](size_t sz) { char* p = w; w += (sz + 255) & ~(size_t)255; return p; };
  unsigned short* xfTb = (unsigned short*)alloc((size_t)C_PAD * P_DIM * 2);  // 32 MB
  unsigned short* Ab   = (unsigned short*)alloc((size_t)N_DIM * N_DIM * 2);  // 32 MB
  float*  colsum = (float*)alloc(N_DIM * 4);
  float*  Sun    = (float*)alloc((size_t)N_DIM * C_PAD * 4);
  unsigned short* t1T = (unsigned short*)alloc((size_t)HID * N_DIM * 2);
  float*  s1     = (float*)alloc((size_t)N_DIM * HID * 4);
  float2* bnp1   = (float2*)alloc(HID * 8);
  unsigned short* t2T = (unsigned short*)alloc((size_t)H2 * N_DIM * 2);
  float*  s2     = (float*)alloc((size_t)N_DIM * H2 * 4);
  float2* bnp2   = (float2*)alloc(H2 * 8);
  unsigned short* s3T = (unsigned short*)alloc((size_t)NCLS * N_DIM * 2);
  if ((size_t)(w - (char*)d_ws) > ws_size) return;  // ws too small: fail loudly

  // zero accumulation targets (ws is poisoned 0xAA before every call)
  hipMemsetAsync(colsum, 0, N_DIM * 4, stream);
  hipMemsetAsync(Sun, 0, (size_t)N_DIM * C_PAD * 4, stream);
  hipMemsetAsync(s1, 0, (size_t)N_DIM * HID * 4, stream);
  hipMemsetAsync(s2, 0, (size_t)N_DIM * H2 * 4, stream);

  k_prep_x<<<dim3(P_DIM / 64, C_PAD / 64), 256, 0, stream>>>(x, xfTb);
  k_prep_A<<<(N_DIM * N_DIM) / 1024, 256, 0, stream>>>(A, Ab);

  k_gemm1<<<dim3(N_DIM / 128, 16), 512, 0, stream>>>(Q, xfTb, Sun, colsum);
  k_fc1<<<N_DIM, 128, 0, stream>>>(Sun, colsum, W1, b1, t1T);
  k_gemm_at<128><<<dim3(N_DIM / 128, 8), 256, 0, stream>>>(Ab, t1T, s1);
  k_bnstats<128><<<HID, 256, 0, stream>>>(s1, g2, beta2, bnp1);
  k_fc2<<<N_DIM, 64, 0, stream>>>(s1, bnp1, W2, b2, t2T);
  k_gemm_at<64><<<dim3(N_DIM / 128, 8), 256, 0, stream>>>(Ab, t2T, s2);
  k_bnstats<64><<<H2, 256, 0, stream>>>(s2, g3, beta3, bnp2);
  k_fc3<<<N_DIM, 64, 0, stream>>>(s2, bnp2, lin_w, lin_b, s3T);
  k_gemm4<<<P_DIM / 64, 256, 0, stream>>>(Q, s3T, out);
}